// Round 16
// baseline (271.300 us; speedup 1.0000x reference)
//
#include <hip/hip_runtime.h>
#include <stdint.h>

typedef short bf16x8 __attribute__((ext_vector_type(8)));
typedef float f32x4 __attribute__((ext_vector_type(4)));
typedef unsigned int uint4v __attribute__((ext_vector_type(4)));
typedef unsigned short ushort4v __attribute__((ext_vector_type(4)));
typedef float float4v __attribute__((ext_vector_type(4)));

#define MROWS 18464      // 32*577
#define SEQ   577
#define CDIM  1024
#define SPAD  640
#define W1ELEMS (2048*1024)
#define W2ELEMS (1024*1024)
#define SQC 0.42466089f   // sqrt(0.125 * log2(e)); applied to q AND k (same buffer)

__device__ __forceinline__ unsigned short f2bf(float f) {
  unsigned int u = __float_as_uint(f);
  u += 0x7fffu + ((u >> 16) & 1u);   // RNE
  return (unsigned short)(u >> 16);
}

__device__ __forceinline__ void load_lds16(const void* g, void* lds) {
  __builtin_amdgcn_global_load_lds(
      (const __attribute__((address_space(1))) unsigned int*)(uint64_t)(uintptr_t)g,
      (__attribute__((address_space(3))) unsigned int*)(unsigned int)(uintptr_t)lds,
      16, 0, 0);
}

// ---------------- LayerNorm: x fp32 -> z bf16 ----------------
__global__ __launch_bounds__(256) void ln_kernel(const float* __restrict__ x,
                                                 const float* __restrict__ g,
                                                 const float* __restrict__ b,
                                                 unsigned short* __restrict__ z) {
  const int row = blockIdx.x;
  const int t = threadIdx.x;
  const float4v v = *(const float4v*)(x + (size_t)row * CDIM + t * 4);
  float s  = v[0] + v[1] + v[2] + v[3];
  float ss = v[0]*v[0] + v[1]*v[1] + v[2]*v[2] + v[3]*v[3];
  #pragma unroll
  for (int off = 1; off < 64; off <<= 1) { s += __shfl_xor(s, off); ss += __shfl_xor(ss, off); }
  __shared__ float rs[4], rss[4];
  const int w = t >> 6, l = t & 63;
  if (l == 0) { rs[w] = s; rss[w] = ss; }
  __syncthreads();
  s = rs[0] + rs[1] + rs[2] + rs[3];
  ss = rss[0] + rss[1] + rss[2] + rss[3];
  const float mu = s * (1.0f / CDIM);
  const float var = ss * (1.0f / CDIM) - mu * mu;
  const float rstd = rsqrtf(var + 1e-5f);
  const float4v gv = *(const float4v*)(g + t * 4);
  const float4v bv = *(const float4v*)(b + t * 4);
  ushort4v o;
  #pragma unroll
  for (int j = 0; j < 4; ++j) o[j] = f2bf((v[j] - mu) * rstd * gv[j] + bv[j]);
  *(ushort4v*)(z + (size_t)row * CDIM + t * 4) = o;
}

// -------- pack+convert weights + zero vt's seq-pad columns --------
__global__ __launch_bounds__(256) void conv_kernel(const float* __restrict__ w_in,
                                                   const float* __restrict__ w_out,
                                                   unsigned short* __restrict__ wqv,
                                                   unsigned short* __restrict__ wo,
                                                   unsigned short* __restrict__ vt) {
  const int idx = blockIdx.x * 256 + threadIdx.x;
  const int e = idx * 4;
  if (e < W1ELEMS) {
    const int row = e >> 10;
    const int srow = row < 1024 ? row : row + 1024;
    const float4v v = *(const float4v*)(w_in + (size_t)srow * 1024 + (e & 1023));
    ushort4v o;
    #pragma unroll
    for (int j = 0; j < 4; ++j) o[j] = f2bf(v[j]);
    *(ushort4v*)(wqv + e) = o;
  } else if (e < W1ELEMS + W2ELEMS) {
    const int e2 = e - W1ELEMS;
    const float4v v = *(const float4v*)(w_out + e2);
    ushort4v o;
    #pragma unroll
    for (int j = 0; j < 4; ++j) o[j] = f2bf(v[j]);
    *(ushort4v*)(wo + e2) = o;
  } else {
    const int pidx = idx - (W1ELEMS + W2ELEMS) / 4;   // 0..262143
    const int ic = pidx >> 3, part = pidx & 7;
    *(uint4v*)(vt + (size_t)ic * SPAD + 576 + part * 8) = (uint4v)0u;
  }
}

// ---------------- qv GEMM (R11-proven): 256x256, 16 waves 64x64, BK=64 dbuf ----------------
__global__ __launch_bounds__(1024, 4) void gemm_qv(const unsigned short* __restrict__ A,
                                                   const unsigned short* __restrict__ B,
                                                   const float* __restrict__ bias,
                                                   unsigned short* __restrict__ qout,
                                                   unsigned short* __restrict__ vtout) {
  __shared__ char smem[131072];  // buf b at b*65536: A [256][64] @0 (32KB), B @32768
  const int t = threadIdx.x;
  const int w = t >> 6, l = t & 63;
  const int L = (blockIdx.x & 7) * 73 + (blockIdx.x >> 3);   // bijective: 584=8*73
  const int p = L >> 3, c = L & 7;
  const int m0 = p * 256, n0 = c * 256;
  const int wm = w >> 2, wn = w & 3;
  const int g4 = (l >> 4) * 4;
  const int fr = l & 15;
  const int fb = (l >> 4) * 16;
  const int sw = (l & 7) << 4;

  f32x4 acc[4][4];
  #pragma unroll
  for (int i = 0; i < 4; ++i)
    #pragma unroll
    for (int j = 0; j < 4; ++j) acc[i][j] = (f32x4)0.0f;

  const int srow = l >> 3;
  const int scol = ((((l & 7) * 16) ^ ((srow & 7) << 4)) >> 1);
  int ra0 = m0 + w * 16 + srow;     if (ra0 > MROWS - 1) ra0 = MROWS - 1;
  int ra1 = m0 + w * 16 + 8 + srow; if (ra1 > MROWS - 1) ra1 = MROWS - 1;
  const unsigned short* pA0 = A + (size_t)ra0 * 1024 + scol;
  const unsigned short* pA1 = A + (size_t)ra1 * 1024 + scol;
  const unsigned short* pB0 = B + (size_t)(n0 + w * 16 + srow) * 1024 + scol;
  const unsigned short* pB1 = pB0 + (size_t)8 * 1024;

  #define STG(kt, buf)                                                     \
    {                                                                      \
      char* const dA_ = smem + (buf) * 65536 + w * 2048;                   \
      char* const dB_ = dA_ + 32768;                                       \
      const int k0_ = (kt) * 64;                                           \
      load_lds16(pA0 + k0_, dA_);                                          \
      load_lds16(pA1 + k0_, dA_ + 1024);                                   \
      load_lds16(pB0 + k0_, dB_);                                          \
      load_lds16(pB1 + k0_, dB_ + 1024);                                   \
    }

  STG(0, 0)
  __syncthreads();

  for (int kb = 0; kb < 16; ++kb) {
    const int b = kb & 1;
    if (kb < 15) STG(kb + 1, b ^ 1)
    const char* Ab = smem + b * 65536;
    const char* Bb = Ab + 32768;
    #pragma unroll
    for (int kk = 0; kk < 2; ++kk) {
      bf16x8 af[4], bfr[4];
      #pragma unroll
      for (int i = 0; i < 4; ++i)
        af[i] = *(const bf16x8*)(Ab + (wm * 64 + i * 16 + fr) * 128 + ((kk * 64 + fb) ^ sw));
      #pragma unroll
      for (int j = 0; j < 4; ++j)
        bfr[j] = *(const bf16x8*)(Bb + (wn * 64 + j * 16 + fr) * 128 + ((kk * 64 + fb) ^ sw));
      #pragma unroll
      for (int i = 0; i < 4; ++i)
        #pragma unroll
        for (int j = 0; j < 4; ++j)
          acc[i][j] = __builtin_amdgcn_mfma_f32_16x16x32_bf16(af[i], bfr[j], acc[i][j], 0, 0, 0);
    }
    __syncthreads();
  }
  #undef STG

  unsigned short* sm = (unsigned short*)smem;   // [64][264] b16 per pass
  const bool isq = (n0 < 1024);
  const float* bb = isq ? (bias + n0) : (bias + 1024 + n0);
  const float scl = isq ? SQC : 1.0f;
  float bcol[4];
  #pragma unroll
  for (int j = 0; j < 4; ++j) bcol[j] = bb[wn * 64 + j * 16 + fr];
  for (int pass = 0; pass < 4; ++pass) {
    if (wm == pass) {
      #pragma unroll
      for (int i = 0; i < 4; ++i)
        #pragma unroll
        for (int j = 0; j < 4; ++j)
          #pragma unroll
          for (int r = 0; r < 4; ++r)
            sm[(i * 16 + g4 + r) * 264 + wn * 64 + j * 16 + fr] =
                f2bf((acc[i][j][r] + bcol[j]) * scl);
    }
    __syncthreads();
    if (isq) {
      #pragma unroll
      for (int it = 0; it < 2; ++it) {
        const int cid = it * 1024 + t;
        const int row = cid >> 5, ch = cid & 31;
        const int grow = m0 + pass * 64 + row;
        if (grow < MROWS)
          *(uint4v*)(qout + (size_t)grow * 1024 + n0 + ch * 8) =
              *(const uint4v*)(sm + row * 264 + ch * 8);
      }
    } else {
      const int tokloc = t & 63, chgrp = t >> 6;   // 16 groups of 16 channels
      const int token = m0 + pass * 64 + tokloc;
      if (token < MROWS) {
        const unsigned int nimg = (unsigned int)token / 577u;
        const int s = token - (int)(nimg * 577u);
        unsigned short* op =
            vtout + ((size_t)nimg * 1024 + (n0 - 1024) + chgrp * 16) * SPAD + s;
        const unsigned short* sp = sm + tokloc * 264 + chgrp * 16;
        #pragma unroll 8
        for (int it = 0; it < 16; ++it)
          op[(size_t)it * SPAD] = sp[it];
      }
    }
    __syncthreads();
  }
}

// ---------------- proj GEMM (R15-proven): 256x128 tile, 16 waves 64x32, BK=64 dbuf ----------------
__global__ __launch_bounds__(1024, 4) void gemm_proj(const unsigned short* __restrict__ A,
                                                     const unsigned short* __restrict__ B,
                                                     const float* __restrict__ bias,
                                                     float* __restrict__ outp) {
  __shared__ char smem[98304];  // buf b at b*49152: A [256][64] @0 (32KB), B [128][64] @32768
  const int t = threadIdx.x;
  const int w = t >> 6, l = t & 63;
  const int L = (blockIdx.x & 7) * 73 + (blockIdx.x >> 3);   // bijective: 584=8*73
  const int p = L >> 3, c = L & 7;
  const int m0 = p * 256, n0 = c * 128;
  const int wm = w >> 2, wn = w & 3;
  const int g4 = (l >> 4) * 4;
  const int fr = l & 15;
  const int fb = (l >> 4) * 16;
  const int sw = (l & 7) << 4;

  f32x4 acc[4][2];
  #pragma unroll
  for (int i = 0; i < 4; ++i)
    #pragma unroll
    for (int j = 0; j < 2; ++j) acc[i][j] = (f32x4)0.0f;

  const int srow = l >> 3;
  const int scol = ((((l & 7) * 16) ^ ((srow & 7) << 4)) >> 1);
  int ra0 = m0 + w * 16 + srow;     if (ra0 > MROWS - 1) ra0 = MROWS - 1;
  int ra1 = m0 + w * 16 + 8 + srow; if (ra1 > MROWS - 1) ra1 = MROWS - 1;
  const unsigned short* pA0 = A + (size_t)ra0 * 1024 + scol;
  const unsigned short* pA1 = A + (size_t)ra1 * 1024 + scol;
  const unsigned short* pB0 = B + (size_t)(n0 + w * 8 + srow) * 1024 + scol;  // 16 waves x 8 rows

  #define STG(kt, buf)                                                     \
    {                                                                      \
      char* const dA_ = smem + (buf) * 49152 + w * 2048;                   \
      const int k0_ = (kt) * 64;                                           \
      load_lds16(pA0 + k0_, dA_);                                          \
      load_lds16(pA1 + k0_, dA_ + 1024);                                   \
      load_lds16(pB0 + k0_, smem + (buf) * 49152 + 32768 + w * 1024);      \
    }

  STG(0, 0)
  __syncthreads();

  for (int kb = 0; kb < 16; ++kb) {
    const int b = kb & 1;
    if (kb < 15) STG(kb + 1, b ^ 1)
    const char* Ab = smem + b * 49152;
    const char* Bb = Ab + 32768;
    #pragma unroll
    for (int kk = 0; kk < 2; ++kk) {
      bf16x8 af[4], bfr[2];
      #pragma unroll
      for (int i = 0; i < 4; ++i)
        af[i] = *(const bf16x8*)(Ab + (wm * 64 + i * 16 + fr) * 128 + ((kk * 64 + fb) ^ sw));
      #pragma unroll
      for (int j = 0; j < 2; ++j)
        bfr[j] = *(const bf16x8*)(Bb + (wn * 32 + j * 16 + fr) * 128 + ((kk * 64 + fb) ^ sw));
      #pragma unroll
      for (int i = 0; i < 4; ++i)
        #pragma unroll
        for (int j = 0; j < 2; ++j)
          acc[i][j] = __builtin_amdgcn_mfma_f32_16x16x32_bf16(af[i], bfr[j], acc[i][j], 0, 0, 0);
    }
    __syncthreads();
  }
  #undef STG

  // fp32 epilogue: eight 32-row passes, [32][132] f32 = 16.9KB
  float* smf = (float*)smem;
  float bcol[2];
  #pragma unroll
  for (int j = 0; j < 2; ++j) bcol[j] = bias[n0 + wn * 32 + j * 16 + fr];
  for (int q8 = 0; q8 < 8; ++q8) {
    if (wm == (q8 >> 1)) {
      const int i0 = (q8 & 1) * 2;
      #pragma unroll
      for (int i2 = 0; i2 < 2; ++i2)
        #pragma unroll
        for (int j = 0; j < 2; ++j)
          #pragma unroll
          for (int r = 0; r < 4; ++r)
            smf[(i2 * 16 + g4 + r) * 132 + wn * 32 + j * 16 + fr] =
                acc[i0 + i2][j][r] + bcol[j];
    }
    __syncthreads();
    {
      const int row = t >> 5, ch = t & 31;        // 32 rows x 128 cols, 1 float4/thread
      const int grow = m0 + q8 * 32 + row;
      if (grow < MROWS)
        *(float4v*)(outp + (size_t)grow * 1024 + n0 + ch * 4) =
            *(const float4v*)(smf + row * 132 + ch * 4);
    }
    __syncthreads();
  }
}

// ---------------- flash attention, k = q ('qq'), no-max softmax ----------------
// 2 waves x 64 q-rows (4 half-groups of 16): each K/V LDS fragment read feeds
// FOUR q-half MFMAs -> LDS reads per block-tile 64KB -> 32KB. 5 blocks/CU.
// Double-buffered staging; grid 2560 XCD-chunked (unchanged).
__global__ __launch_bounds__(128) void attn_kernel(const unsigned short* __restrict__ qbuf,
                                                   const unsigned short* __restrict__ vt,
                                                   unsigned short* __restrict__ out) {
  __shared__ char smem[32768];  // buf b at b*16384: K 8KB, V^T 8KB
  const int t = threadIdx.x, w = t >> 6, l = t & 63;
  const int g = l >> 4, fr = l & 15;
  const int bid = blockIdx.x;
  const int xcd = bid & 7, idx = bid >> 3;
  const int nhl = idx / 5;
  const int qb = idx - nhl * 5;
  const int nh = xcd * 64 + nhl;
  const int n = nh >> 4, h = nh & 15;
  const size_t rowbase = (size_t)n * SEQ;
  const int sw = (l & 7) << 4;

  // Q B-fragments: wave w owns q-rows w*64 + h2*16 + fr (4 half-groups)
  bf16x8 bq[4][2];
  #pragma unroll
  for (int h2 = 0; h2 < 4; ++h2) {
    const unsigned short* qp =
        qbuf + (rowbase + qb * 128 + w * 64 + h2 * 16 + fr) * 1024 + h * 64 + g * 8;
    bq[h2][0] = *(const bf16x8*)qp;
    bq[h2][1] = *(const bf16x8*)(qp + 32);
  }

  const int srow = l >> 3;
  const int scolE = ((((l & 7) * 16) ^ ((srow & 7) << 4)) >> 1);
  // wave w stages K rows w*32+c*8+srow and V d-rows w*32+c*8+srow (c=0..3)
  const unsigned short* ksrc = qbuf + (rowbase + w * 32 + srow) * 1024 + h * 64 + scolE;
  const unsigned short* vsrc = vt + ((size_t)nh * 64 + w * 32 + srow) * SPAD + scolE;

  f32x4 acc[4][4];
  #pragma unroll
  for (int h2 = 0; h2 < 4; ++h2)
    #pragma unroll
    for (int cf = 0; cf < 4; ++cf) acc[h2][cf] = (f32x4)0.0f;
  float l_run[4] = {0.0f, 0.0f, 0.0f, 0.0f};

  #define ASTG(kb_, buf_)                                                          \
    {                                                                              \
      char* kdst = smem + (buf_) * 16384 + (w * 32) * 128;                         \
      char* vdst = kdst + 8192;                                                    \
      _Pragma("unroll")                                                            \
      for (int c2 = 0; c2 < 4; ++c2) {                                             \
        load_lds16(ksrc + (size_t)((kb_) * 64 + c2 * 8) * 1024, kdst + c2 * 1024); \
        load_lds16(vsrc + c2 * 8 * SPAD + (kb_) * 64, vdst + c2 * 1024);           \
      }                                                                            \
    }

  ASTG(0, 0)
  __syncthreads();

  for (int kb = 0; kb < 10; ++kb) {
    const int b = kb & 1;
    const char* kbuf = smem + b * 16384;
    const char* vbuf = kbuf + 8192;

    if (kb < 9) ASTG(kb + 1, b ^ 1)

    // S^T for 4 half-groups; each af read feeds 4 MFMAs
    f32x4 s4[4][4];
    #pragma unroll
    for (int h2 = 0; h2 < 4; ++h2)
      #pragma unroll
      for (int cf = 0; cf < 4; ++cf) s4[h2][cf] = (f32x4)0.0f;
    __builtin_amdgcn_s_setprio(1);
    #pragma unroll
    for (int kk = 0; kk < 2; ++kk)
      #pragma unroll
      for (int cf = 0; cf < 4; ++cf) {
        const bf16x8 af = *(const bf16x8*)(kbuf + (cf * 16 + fr) * 128 + ((kk * 64 + g * 16) ^ sw));
        #pragma unroll
        for (int h2 = 0; h2 < 4; ++h2)
          s4[h2][cf] = __builtin_amdgcn_mfma_f32_16x16x32_bf16(af, bq[h2][kk], s4[h2][cf], 0, 0, 0);
      }
    __builtin_amdgcn_s_setprio(0);

    if (kb == 9) {  // 577 = 9*64 + 1: only s_local == 0 valid
      #pragma unroll
      for (int h2 = 0; h2 < 4; ++h2) {
        #pragma unroll
        for (int cf = 0; cf < 4; ++cf)
          #pragma unroll
          for (int r = 0; r < 4; ++r)
            if (cf != 0 || r != 0) s4[h2][cf][r] = -__builtin_inff();
        s4[h2][0][0] = (g == 0) ? s4[h2][0][0] : -__builtin_inff();
      }
    }

    // per half-group: softmax (no max; bounded inputs) + pack + permlane + PV
    #pragma unroll
    for (int h2 = 0; h2 < 4; ++h2) {
      float sum = 0.0f;
      #pragma unroll
      for (int cf = 0; cf < 4; ++cf)
        #pragma unroll
        for (int r = 0; r < 4; ++r) {
          const float p2 = __builtin_amdgcn_exp2f(s4[h2][cf][r]);
          s4[h2][cf][r] = p2;
          sum += p2;
        }
      sum += __shfl_xor(sum, 16);
      sum += __shfl_xor(sum, 32);
      l_run[h2] += sum;

      unsigned int pka[4], pkb[4];
      #pragma unroll
      for (int cf = 0; cf < 4; ++cf) {
        asm("v_cvt_pk_bf16_f32 %0, %1, %2" : "=v"(pka[cf]) : "v"(s4[h2][cf][0]), "v"(s4[h2][cf][1]));
        asm("v_cvt_pk_bf16_f32 %0, %1, %2" : "=v"(pkb[cf]) : "v"(s4[h2][cf][2]), "v"(s4[h2][cf][3]));
      }
      bf16x8 ap[2];
      #pragma unroll
      for (int kk = 0; kk < 2; ++kk) {
        unsigned int a0 = pka[2 * kk], b0 = pka[2 * kk + 1];
        unsigned int a1 = pkb[2 * kk], b1 = pkb[2 * kk + 1];
        asm("v_permlane32_swap_b32 %0, %1" : "+v"(a0), "+v"(b0));
        asm("v_permlane16_swap_b32 %0, %1" : "+v"(a0), "+v"(b0));
        asm("v_permlane32_swap_b32 %0, %1" : "+v"(a1), "+v"(b1));
        asm("v_permlane16_swap_b32 %0, %1" : "+v"(a1), "+v"(b1));
        union { unsigned int i[4]; bf16x8 v; } u;
        u.i[0] = a0; u.i[1] = a1; u.i[2] = b0; u.i[3] = b1;
        ap[kk] = u.v;
      }
      __builtin_amdgcn_s_setprio(1);
      #pragma unroll
      for (int kk = 0; kk < 2; ++kk)
        #pragma unroll
        for (int cf = 0; cf < 4; ++cf) {
          const bf16x8 bv = *(const bf16x8*)(vbuf + (cf * 16 + fr) * 128 + ((kk * 64 + g * 16) ^ sw));
          acc[h2][cf] = __builtin_amdgcn_mfma_f32_16x16x32_bf16(ap[kk], bv, acc[h2][cf], 0, 0, 0);
        }
      __builtin_amdgcn_s_setprio(0);
    }

    __syncthreads();
  }
  #undef ASTG

  #pragma unroll
  for (int h2 = 0; h2 < 4; ++h2) {
    const float rcp = 1.0f / l_run[h2];
    #pragma unroll
    for (int r = 0; r < 4; ++r) {
      const float rr = __shfl(rcp, g * 4 + r);
      const int qg = qb * 128 + w * 64 + h2 * 16 + g * 4 + r;
      if (qg < SEQ) {
        #pragma unroll
        for (int cf = 0; cf < 4; ++cf)
          out[(rowbase + qg) * 1024 + h * 64 + cf * 16 + fr] = f2bf(acc[h2][cf][r] * rr);
      }
    }
  }
}

extern "C" void kernel_launch(void* const* d_in, const int* in_sizes, int n_in,
                              void* d_out, int out_size, void* d_ws, size_t ws_size,
                              hipStream_t stream) {
  const float* x     = (const float*)d_in[0];
  const float* ln_g  = (const float*)d_in[1];
  const float* ln_b  = (const float*)d_in[2];
  const float* w_in  = (const float*)d_in[3];
  const float* b_in  = (const float*)d_in[4];
  const float* w_out = (const float*)d_in[5];
  const float* b_out = (const float*)d_in[6];

  unsigned short* z    = (unsigned short*)d_ws;            // [MROWS][1024] bf16; reused as attn_out
  unsigned short* qbuf = z + (size_t)MROWS * 1024;         // [MROWS][1024] bf16 (q = k, pre-scaled)
  unsigned short* vt   = qbuf + (size_t)MROWS * 1024;      // [32*1024][640] bf16 (V^T)
  unsigned short* wqv  = vt + (size_t)512 * 64 * SPAD;     // [2048][1024] bf16
  unsigned short* wo   = wqv + (size_t)2048 * 1024;        // [1024][1024] bf16

  ln_kernel<<<MROWS, 256, 0, stream>>>(x, ln_g, ln_b, z);
  conv_kernel<<<4096, 256, 0, stream>>>(w_in, w_out, wqv, wo, vt);
  gemm_qv<<<584, 1024, 0, stream>>>(z, wqv, b_in, qbuf, vt);
  attn_kernel<<<2560, 128, 0, stream>>>(qbuf, vt, z);
  gemm_proj<<<584, 1024, 0, stream>>>(z, wo, b_out, (float*)d_out);
}

// Round 17
// 248.510 us; speedup vs baseline: 1.0917x; 1.0917x over previous
//
#include <hip/hip_runtime.h>
#include <stdint.h>

typedef short bf16x8 __attribute__((ext_vector_type(8)));
typedef float f32x4 __attribute__((ext_vector_type(4)));
typedef unsigned int uint4v __attribute__((ext_vector_type(4)));
typedef unsigned short ushort4v __attribute__((ext_vector_type(4)));
typedef float float4v __attribute__((ext_vector_type(4)));

#define MROWS 18464      // 32*577
#define SEQ   577
#define CDIM  1024
#define SPAD  640
#define W1ELEMS (2048*1024)
#define W2ELEMS (1024*1024)
#define SQC 0.42466089f   // sqrt(0.125 * log2(e)); applied to q AND k (same buffer)

__device__ __forceinline__ unsigned short f2bf(float f) {
  unsigned int u = __float_as_uint(f);
  u += 0x7fffu + ((u >> 16) & 1u);   // RNE
  return (unsigned short)(u >> 16);
}

__device__ __forceinline__ void load_lds16(const void* g, void* lds) {
  __builtin_amdgcn_global_load_lds(
      (const __attribute__((address_space(1))) unsigned int*)(uint64_t)(uintptr_t)g,
      (__attribute__((address_space(3))) unsigned int*)(unsigned int)(uintptr_t)lds,
      16, 0, 0);
}

// ---------------- LayerNorm: x fp32 -> z bf16 ----------------
__global__ __launch_bounds__(256) void ln_kernel(const float* __restrict__ x,
                                                 const float* __restrict__ g,
                                                 const float* __restrict__ b,
                                                 unsigned short* __restrict__ z) {
  const int row = blockIdx.x;
  const int t = threadIdx.x;
  const float4v v = *(const float4v*)(x + (size_t)row * CDIM + t * 4);
  float s  = v[0] + v[1] + v[2] + v[3];
  float ss = v[0]*v[0] + v[1]*v[1] + v[2]*v[2] + v[3]*v[3];
  #pragma unroll
  for (int off = 1; off < 64; off <<= 1) { s += __shfl_xor(s, off); ss += __shfl_xor(ss, off); }
  __shared__ float rs[4], rss[4];
  const int w = t >> 6, l = t & 63;
  if (l == 0) { rs[w] = s; rss[w] = ss; }
  __syncthreads();
  s = rs[0] + rs[1] + rs[2] + rs[3];
  ss = rss[0] + rss[1] + rss[2] + rss[3];
  const float mu = s * (1.0f / CDIM);
  const float var = ss * (1.0f / CDIM) - mu * mu;
  const float rstd = rsqrtf(var + 1e-5f);
  const float4v gv = *(const float4v*)(g + t * 4);
  const float4v bv = *(const float4v*)(b + t * 4);
  ushort4v o;
  #pragma unroll
  for (int j = 0; j < 4; ++j) o[j] = f2bf((v[j] - mu) * rstd * gv[j] + bv[j]);
  *(ushort4v*)(z + (size_t)row * CDIM + t * 4) = o;
}

// -------- pack+convert weights + zero vt's seq-pad columns --------
__global__ __launch_bounds__(256) void conv_kernel(const float* __restrict__ w_in,
                                                   const float* __restrict__ w_out,
                                                   unsigned short* __restrict__ wqv,
                                                   unsigned short* __restrict__ wo,
                                                   unsigned short* __restrict__ vt) {
  const int idx = blockIdx.x * 256 + threadIdx.x;
  const int e = idx * 4;
  if (e < W1ELEMS) {
    const int row = e >> 10;
    const int srow = row < 1024 ? row : row + 1024;
    const float4v v = *(const float4v*)(w_in + (size_t)srow * 1024 + (e & 1023));
    ushort4v o;
    #pragma unroll
    for (int j = 0; j < 4; ++j) o[j] = f2bf(v[j]);
    *(ushort4v*)(wqv + e) = o;
  } else if (e < W1ELEMS + W2ELEMS) {
    const int e2 = e - W1ELEMS;
    const float4v v = *(const float4v*)(w_out + e2);
    ushort4v o;
    #pragma unroll
    for (int j = 0; j < 4; ++j) o[j] = f2bf(v[j]);
    *(ushort4v*)(wo + e2) = o;
  } else {
    const int pidx = idx - (W1ELEMS + W2ELEMS) / 4;   // 0..262143
    const int ic = pidx >> 3, part = pidx & 7;
    *(uint4v*)(vt + (size_t)ic * SPAD + 576 + part * 8) = (uint4v)0u;
  }
}

// ---------------- qv GEMM (R11-proven): 256x256, 16 waves 64x64, BK=64 dbuf ----------------
__global__ __launch_bounds__(1024, 4) void gemm_qv(const unsigned short* __restrict__ A,
                                                   const unsigned short* __restrict__ B,
                                                   const float* __restrict__ bias,
                                                   unsigned short* __restrict__ qout,
                                                   unsigned short* __restrict__ vtout) {
  __shared__ char smem[131072];  // buf b at b*65536: A [256][64] @0 (32KB), B @32768
  const int t = threadIdx.x;
  const int w = t >> 6, l = t & 63;
  const int L = (blockIdx.x & 7) * 73 + (blockIdx.x >> 3);   // bijective: 584=8*73
  const int p = L >> 3, c = L & 7;
  const int m0 = p * 256, n0 = c * 256;
  const int wm = w >> 2, wn = w & 3;
  const int g4 = (l >> 4) * 4;
  const int fr = l & 15;
  const int fb = (l >> 4) * 16;
  const int sw = (l & 7) << 4;

  f32x4 acc[4][4];
  #pragma unroll
  for (int i = 0; i < 4; ++i)
    #pragma unroll
    for (int j = 0; j < 4; ++j) acc[i][j] = (f32x4)0.0f;

  const int srow = l >> 3;
  const int scol = ((((l & 7) * 16) ^ ((srow & 7) << 4)) >> 1);
  int ra0 = m0 + w * 16 + srow;     if (ra0 > MROWS - 1) ra0 = MROWS - 1;
  int ra1 = m0 + w * 16 + 8 + srow; if (ra1 > MROWS - 1) ra1 = MROWS - 1;
  const unsigned short* pA0 = A + (size_t)ra0 * 1024 + scol;
  const unsigned short* pA1 = A + (size_t)ra1 * 1024 + scol;
  const unsigned short* pB0 = B + (size_t)(n0 + w * 16 + srow) * 1024 + scol;
  const unsigned short* pB1 = pB0 + (size_t)8 * 1024;

  #define STG(kt, buf)                                                     \
    {                                                                      \
      char* const dA_ = smem + (buf) * 65536 + w * 2048;                   \
      char* const dB_ = dA_ + 32768;                                       \
      const int k0_ = (kt) * 64;                                           \
      load_lds16(pA0 + k0_, dA_);                                          \
      load_lds16(pA1 + k0_, dA_ + 1024);                                   \
      load_lds16(pB0 + k0_, dB_);                                          \
      load_lds16(pB1 + k0_, dB_ + 1024);                                   \
    }

  STG(0, 0)
  __syncthreads();

  for (int kb = 0; kb < 16; ++kb) {
    const int b = kb & 1;
    if (kb < 15) STG(kb + 1, b ^ 1)
    const char* Ab = smem + b * 65536;
    const char* Bb = Ab + 32768;
    #pragma unroll
    for (int kk = 0; kk < 2; ++kk) {
      bf16x8 af[4], bfr[4];
      #pragma unroll
      for (int i = 0; i < 4; ++i)
        af[i] = *(const bf16x8*)(Ab + (wm * 64 + i * 16 + fr) * 128 + ((kk * 64 + fb) ^ sw));
      #pragma unroll
      for (int j = 0; j < 4; ++j)
        bfr[j] = *(const bf16x8*)(Bb + (wn * 64 + j * 16 + fr) * 128 + ((kk * 64 + fb) ^ sw));
      #pragma unroll
      for (int i = 0; i < 4; ++i)
        #pragma unroll
        for (int j = 0; j < 4; ++j)
          acc[i][j] = __builtin_amdgcn_mfma_f32_16x16x32_bf16(af[i], bfr[j], acc[i][j], 0, 0, 0);
    }
    __syncthreads();
  }
  #undef STG

  unsigned short* sm = (unsigned short*)smem;   // [64][264] b16 per pass
  const bool isq = (n0 < 1024);
  const float* bb = isq ? (bias + n0) : (bias + 1024 + n0);
  const float scl = isq ? SQC : 1.0f;
  float bcol[4];
  #pragma unroll
  for (int j = 0; j < 4; ++j) bcol[j] = bb[wn * 64 + j * 16 + fr];
  for (int pass = 0; pass < 4; ++pass) {
    if (wm == pass) {
      #pragma unroll
      for (int i = 0; i < 4; ++i)
        #pragma unroll
        for (int j = 0; j < 4; ++j)
          #pragma unroll
          for (int r = 0; r < 4; ++r)
            sm[(i * 16 + g4 + r) * 264 + wn * 64 + j * 16 + fr] =
                f2bf((acc[i][j][r] + bcol[j]) * scl);
    }
    __syncthreads();
    if (isq) {
      #pragma unroll
      for (int it = 0; it < 2; ++it) {
        const int cid = it * 1024 + t;
        const int row = cid >> 5, ch = cid & 31;
        const int grow = m0 + pass * 64 + row;
        if (grow < MROWS)
          *(uint4v*)(qout + (size_t)grow * 1024 + n0 + ch * 8) =
              *(const uint4v*)(sm + row * 264 + ch * 8);
      }
    } else {
      const int tokloc = t & 63, chgrp = t >> 6;   // 16 groups of 16 channels
      const int token = m0 + pass * 64 + tokloc;
      if (token < MROWS) {
        const unsigned int nimg = (unsigned int)token / 577u;
        const int s = token - (int)(nimg * 577u);
        unsigned short* op =
            vtout + ((size_t)nimg * 1024 + (n0 - 1024) + chgrp * 16) * SPAD + s;
        const unsigned short* sp = sm + tokloc * 264 + chgrp * 16;
        #pragma unroll 8
        for (int it = 0; it < 16; ++it)
          op[(size_t)it * SPAD] = sp[it];
      }
    }
    __syncthreads();
  }
}

// ---------------- proj GEMM (R15-proven): 256x128 tile, 16 waves 64x32, BK=64 dbuf ----------------
__global__ __launch_bounds__(1024, 4) void gemm_proj(const unsigned short* __restrict__ A,
                                                     const unsigned short* __restrict__ B,
                                                     const float* __restrict__ bias,
                                                     float* __restrict__ outp) {
  __shared__ char smem[98304];  // buf b at b*49152: A [256][64] @0 (32KB), B [128][64] @32768
  const int t = threadIdx.x;
  const int w = t >> 6, l = t & 63;
  const int L = (blockIdx.x & 7) * 73 + (blockIdx.x >> 3);   // bijective: 584=8*73
  const int p = L >> 3, c = L & 7;
  const int m0 = p * 256, n0 = c * 128;
  const int wm = w >> 2, wn = w & 3;
  const int g4 = (l >> 4) * 4;
  const int fr = l & 15;
  const int fb = (l >> 4) * 16;
  const int sw = (l & 7) << 4;

  f32x4 acc[4][2];
  #pragma unroll
  for (int i = 0; i < 4; ++i)
    #pragma unroll
    for (int j = 0; j < 2; ++j) acc[i][j] = (f32x4)0.0f;

  const int srow = l >> 3;
  const int scol = ((((l & 7) * 16) ^ ((srow & 7) << 4)) >> 1);
  int ra0 = m0 + w * 16 + srow;     if (ra0 > MROWS - 1) ra0 = MROWS - 1;
  int ra1 = m0 + w * 16 + 8 + srow; if (ra1 > MROWS - 1) ra1 = MROWS - 1;
  const unsigned short* pA0 = A + (size_t)ra0 * 1024 + scol;
  const unsigned short* pA1 = A + (size_t)ra1 * 1024 + scol;
  const unsigned short* pB0 = B + (size_t)(n0 + w * 8 + srow) * 1024 + scol;  // 16 waves x 8 rows

  #define STG(kt, buf)                                                     \
    {                                                                      \
      char* const dA_ = smem + (buf) * 49152 + w * 2048;                   \
      const int k0_ = (kt) * 64;                                           \
      load_lds16(pA0 + k0_, dA_);                                          \
      load_lds16(pA1 + k0_, dA_ + 1024);                                   \
      load_lds16(pB0 + k0_, smem + (buf) * 49152 + 32768 + w * 1024);      \
    }

  STG(0, 0)
  __syncthreads();

  for (int kb = 0; kb < 16; ++kb) {
    const int b = kb & 1;
    if (kb < 15) STG(kb + 1, b ^ 1)
    const char* Ab = smem + b * 49152;
    const char* Bb = Ab + 32768;
    #pragma unroll
    for (int kk = 0; kk < 2; ++kk) {
      bf16x8 af[4], bfr[2];
      #pragma unroll
      for (int i = 0; i < 4; ++i)
        af[i] = *(const bf16x8*)(Ab + (wm * 64 + i * 16 + fr) * 128 + ((kk * 64 + fb) ^ sw));
      #pragma unroll
      for (int j = 0; j < 2; ++j)
        bfr[j] = *(const bf16x8*)(Bb + (wn * 32 + j * 16 + fr) * 128 + ((kk * 64 + fb) ^ sw));
      #pragma unroll
      for (int i = 0; i < 4; ++i)
        #pragma unroll
        for (int j = 0; j < 2; ++j)
          acc[i][j] = __builtin_amdgcn_mfma_f32_16x16x32_bf16(af[i], bfr[j], acc[i][j], 0, 0, 0);
    }
    __syncthreads();
  }
  #undef STG

  // fp32 epilogue: eight 32-row passes, [32][132] f32 = 16.9KB
  float* smf = (float*)smem;
  float bcol[2];
  #pragma unroll
  for (int j = 0; j < 2; ++j) bcol[j] = bias[n0 + wn * 32 + j * 16 + fr];
  for (int q8 = 0; q8 < 8; ++q8) {
    if (wm == (q8 >> 1)) {
      const int i0 = (q8 & 1) * 2;
      #pragma unroll
      for (int i2 = 0; i2 < 2; ++i2)
        #pragma unroll
        for (int j = 0; j < 2; ++j)
          #pragma unroll
          for (int r = 0; r < 4; ++r)
            smf[(i2 * 16 + g4 + r) * 132 + wn * 32 + j * 16 + fr] =
                acc[i0 + i2][j][r] + bcol[j];
    }
    __syncthreads();
    {
      const int row = t >> 5, ch = t & 31;        // 32 rows x 128 cols, 1 float4/thread
      const int grow = m0 + q8 * 32 + row;
      if (grow < MROWS)
        *(float4v*)(outp + (size_t)grow * 1024 + n0 + ch * 4) =
            *(const float4v*)(smf + row * 132 + ch * 4);
    }
    __syncthreads();
  }
}

// ---------------- flash attention (R15-proven 4-wave) + T5 setprio ----------------
// QBLK=128: each wave owns 2x16 q-rows; K/V LDS fragments read ONCE feed both
// halves. Double-buffered staging. 1-D grid 2560, XCD-chunked.
__global__ __launch_bounds__(256) void attn_kernel(const unsigned short* __restrict__ qbuf,
                                                   const unsigned short* __restrict__ vt,
                                                   unsigned short* __restrict__ out) {
  __shared__ char smem[32768];  // buf b at b*16384: K 8KB, V^T 8KB
  const int t = threadIdx.x, w = t >> 6, l = t & 63;
  const int g = l >> 4, fr = l & 15;
  const int bid = blockIdx.x;
  const int xcd = bid & 7, idx = bid >> 3;
  const int nhl = idx / 5;
  const int qb = idx - nhl * 5;
  const int nh = xcd * 64 + nhl;
  const int n = nh >> 4, h = nh & 15;
  const size_t rowbase = (size_t)n * SEQ;
  const int sw = (l & 7) << 4;

  bf16x8 bq[2][2];
  #pragma unroll
  for (int half = 0; half < 2; ++half) {
    const unsigned short* qp =
        qbuf + (rowbase + qb * 128 + half * 64 + w * 16 + fr) * 1024 + h * 64 + g * 8;
    bq[half][0] = *(const bf16x8*)qp;
    bq[half][1] = *(const bf16x8*)(qp + 32);
  }

  const int srow = l >> 3;
  const int scolE = ((((l & 7) * 16) ^ ((srow & 7) << 4)) >> 1);
  const unsigned short* ksrc = qbuf + (rowbase + w * 16 + srow) * 1024 + h * 64 + scolE;
  const unsigned short* vsrc = vt + ((size_t)nh * 64 + w * 16 + srow) * SPAD + scolE;

  f32x4 acc[2][4];
  #pragma unroll
  for (int half = 0; half < 2; ++half)
    #pragma unroll
    for (int cf = 0; cf < 4; ++cf) acc[half][cf] = (f32x4)0.0f;
  float l_run[2] = {0.0f, 0.0f};

  {
    char* kdst = smem + (w * 16) * 128;
    char* vdst = smem + 8192 + (w * 16) * 128;
    load_lds16(ksrc, kdst);
    load_lds16(ksrc + (size_t)8 * 1024, kdst + 1024);
    load_lds16(vsrc, vdst);
    load_lds16(vsrc + 8 * SPAD, vdst + 1024);
  }
  __syncthreads();

  for (int kb = 0; kb < 10; ++kb) {
    const int b = kb & 1;
    const char* kbuf = smem + b * 16384;
    const char* vbuf = kbuf + 8192;

    if (kb < 9) {
      char* kdst = smem + (b ^ 1) * 16384 + (w * 16) * 128;
      char* vdst = kdst + 8192;
      load_lds16(ksrc + (size_t)((kb + 1) * 64) * 1024, kdst);
      load_lds16(ksrc + (size_t)((kb + 1) * 64 + 8) * 1024, kdst + 1024);
      load_lds16(vsrc + (kb + 1) * 64, vdst);
      load_lds16(vsrc + 8 * SPAD + (kb + 1) * 64, vdst + 1024);
    }

    f32x4 s4[2][4];
    #pragma unroll
    for (int half = 0; half < 2; ++half)
      #pragma unroll
      for (int cf = 0; cf < 4; ++cf) s4[half][cf] = (f32x4)0.0f;
    __builtin_amdgcn_s_setprio(1);
    #pragma unroll
    for (int kk = 0; kk < 2; ++kk)
      #pragma unroll
      for (int cf = 0; cf < 4; ++cf) {
        const bf16x8 af = *(const bf16x8*)(kbuf + (cf * 16 + fr) * 128 + ((kk * 64 + g * 16) ^ sw));
        s4[0][cf] = __builtin_amdgcn_mfma_f32_16x16x32_bf16(af, bq[0][kk], s4[0][cf], 0, 0, 0);
        s4[1][cf] = __builtin_amdgcn_mfma_f32_16x16x32_bf16(af, bq[1][kk], s4[1][cf], 0, 0, 0);
      }
    __builtin_amdgcn_s_setprio(0);

    if (kb == 9) {
      #pragma unroll
      for (int half = 0; half < 2; ++half) {
        #pragma unroll
        for (int cf = 0; cf < 4; ++cf)
          #pragma unroll
          for (int r = 0; r < 4; ++r)
            if (cf != 0 || r != 0) s4[half][cf][r] = -__builtin_inff();
        s4[half][0][0] = (g == 0) ? s4[half][0][0] : -__builtin_inff();
      }
    }

    bf16x8 ap[2][2];
    #pragma unroll
    for (int half = 0; half < 2; ++half) {
      float sum = 0.0f;
      #pragma unroll
      for (int cf = 0; cf < 4; ++cf)
        #pragma unroll
        for (int r = 0; r < 4; ++r) {
          const float p2 = __builtin_amdgcn_exp2f(s4[half][cf][r]);
          s4[half][cf][r] = p2;
          sum += p2;
        }
      sum += __shfl_xor(sum, 16);
      sum += __shfl_xor(sum, 32);
      l_run[half] += sum;

      unsigned int pka[4], pkb[4];
      #pragma unroll
      for (int cf = 0; cf < 4; ++cf) {
        asm("v_cvt_pk_bf16_f32 %0, %1, %2" : "=v"(pka[cf]) : "v"(s4[half][cf][0]), "v"(s4[half][cf][1]));
        asm("v_cvt_pk_bf16_f32 %0, %1, %2" : "=v"(pkb[cf]) : "v"(s4[half][cf][2]), "v"(s4[half][cf][3]));
      }
      #pragma unroll
      for (int kk = 0; kk < 2; ++kk) {
        unsigned int a0 = pka[2 * kk], b0 = pka[2 * kk + 1];
        unsigned int a1 = pkb[2 * kk], b1 = pkb[2 * kk + 1];
        asm("v_permlane32_swap_b32 %0, %1" : "+v"(a0), "+v"(b0));
        asm("v_permlane16_swap_b32 %0, %1" : "+v"(a0), "+v"(b0));
        asm("v_permlane32_swap_b32 %0, %1" : "+v"(a1), "+v"(b1));
        asm("v_permlane16_swap_b32 %0, %1" : "+v"(a1), "+v"(b1));
        union { unsigned int i[4]; bf16x8 v; } u;
        u.i[0] = a0; u.i[1] = a1; u.i[2] = b0; u.i[3] = b1;
        ap[half][kk] = u.v;
      }
    }

    __builtin_amdgcn_s_setprio(1);
    #pragma unroll
    for (int kk = 0; kk < 2; ++kk)
      #pragma unroll
      for (int cf = 0; cf < 4; ++cf) {
        const bf16x8 bv = *(const bf16x8*)(vbuf + (cf * 16 + fr) * 128 + ((kk * 64 + g * 16) ^ sw));
        acc[0][cf] = __builtin_amdgcn_mfma_f32_16x16x32_bf16(ap[0][kk], bv, acc[0][cf], 0, 0, 0);
        acc[1][cf] = __builtin_amdgcn_mfma_f32_16x16x32_bf16(ap[1][kk], bv, acc[1][cf], 0, 0, 0);
      }
    __builtin_amdgcn_s_setprio(0);

    __syncthreads();
  }

  #pragma unroll
  for (int half = 0; half < 2; ++half) {
    const float rcp = 1.0f / l_run[half];
    #pragma unroll
    for (int r = 0; r < 4; ++r) {
      const float rr = __shfl(rcp, g * 4 + r);
      const int qg = qb * 128 + half * 64 + w * 16 + g * 4 + r;
      if (qg < SEQ) {
        #pragma unroll
        for (int cf = 0; cf < 4; ++cf)
          out[(rowbase + qg) * 1024 + h * 64 + cf * 16 + fr] = f2bf(acc[half][cf][r] * rr);
      }
    }
  }
}

extern "C" void kernel_launch(void* const* d_in, const int* in_sizes, int n_in,
                              void* d_out, int out_size, void* d_ws, size_t ws_size,
                              hipStream_t stream) {
  const float* x     = (const float*)d_in[0];
  const float* ln_g  = (const float*)d_in[1];
  const float* ln_b  = (const float*)d_in[2];
  const float* w_in  = (const float*)d_in[3];
  const float* b_in  = (const float*)d_in[4];
  const float* w_out = (const float*)d_in[5];
  const float* b_out = (const float*)d_in[6];

  unsigned short* z    = (unsigned short*)d_ws;            // [MROWS][1024] bf16; reused as attn_out
  unsigned short* qbuf = z + (size_t)MROWS * 1024;         // [MROWS][1024] bf16 (q = k, pre-scaled)
  unsigned short* vt   = qbuf + (size_t)MROWS * 1024;      // [32*1024][640] bf16 (V^T)
  unsigned short* wqv  = vt + (size_t)512 * 64 * SPAD;     // [2048][1024] bf16
  unsigned short* wo   = wqv + (size_t)2048 * 1024;        // [1024][1024] bf16

  ln_kernel<<<MROWS, 256, 0, stream>>>(x, ln_g, ln_b, z);
  conv_kernel<<<4096, 256, 0, stream>>>(w_in, w_out, wqv, wo, vt);
  gemm_qv<<<584, 1024, 0, stream>>>(z, wqv, b_in, qbuf, vt);
  attn_kernel<<<2560, 256, 0, stream>>>(qbuf, vt, z);
  gemm_proj<<<584, 1024, 0, stream>>>(z, wo, b_out, (float*)d_out);
}

// Round 18
// 239.303 us; speedup vs baseline: 1.1337x; 1.0385x over previous
//
#include <hip/hip_runtime.h>
#include <stdint.h>

typedef short bf16x8 __attribute__((ext_vector_type(8)));
typedef float f32x4 __attribute__((ext_vector_type(4)));
typedef unsigned int uint4v __attribute__((ext_vector_type(4)));
typedef unsigned short ushort4v __attribute__((ext_vector_type(4)));
typedef float float4v __attribute__((ext_vector_type(4)));

#define MROWS 18464      // 32*577
#define SEQ   577
#define CDIM  1024
#define SPAD  640
#define W1ELEMS (2048*1024)
#define W2ELEMS (1024*1024)
#define SQC 0.42466089f   // sqrt(0.125 * log2(e)); applied to q AND k (same buffer)

__device__ __forceinline__ unsigned short f2bf(float f) {
  unsigned int u = __float_as_uint(f);
  u += 0x7fffu + ((u >> 16) & 1u);   // RNE
  return (unsigned short)(u >> 16);
}

__device__ __forceinline__ void load_lds16(const void* g, void* lds) {
  __builtin_amdgcn_global_load_lds(
      (const __attribute__((address_space(1))) unsigned int*)(uint64_t)(uintptr_t)g,
      (__attribute__((address_space(3))) unsigned int*)(unsigned int)(uintptr_t)lds,
      16, 0, 0);
}

// ---------------- fused prep: LN rows (bid < MROWS) + weight convert/pad ----------------
__global__ __launch_bounds__(256) void prep_kernel(const float* __restrict__ x,
                                                   const float* __restrict__ g,
                                                   const float* __restrict__ b,
                                                   const float* __restrict__ w_in,
                                                   const float* __restrict__ w_out,
                                                   unsigned short* __restrict__ z,
                                                   unsigned short* __restrict__ wqv,
                                                   unsigned short* __restrict__ wo,
                                                   unsigned short* __restrict__ vt) {
  const int bid = blockIdx.x;
  const int t = threadIdx.x;
  if (bid < MROWS) {
    const int row = bid;
    const float4v v = *(const float4v*)(x + (size_t)row * CDIM + t * 4);
    float s  = v[0] + v[1] + v[2] + v[3];
    float ss = v[0]*v[0] + v[1]*v[1] + v[2]*v[2] + v[3]*v[3];
    #pragma unroll
    for (int off = 1; off < 64; off <<= 1) { s += __shfl_xor(s, off); ss += __shfl_xor(ss, off); }
    __shared__ float rs[4], rss[4];
    const int w = t >> 6, l = t & 63;
    if (l == 0) { rs[w] = s; rss[w] = ss; }
    __syncthreads();
    s = rs[0] + rs[1] + rs[2] + rs[3];
    ss = rss[0] + rss[1] + rss[2] + rss[3];
    const float mu = s * (1.0f / CDIM);
    const float var = ss * (1.0f / CDIM) - mu * mu;
    const float rstd = rsqrtf(var + 1e-5f);
    const float4v gv = *(const float4v*)(g + t * 4);
    const float4v bv = *(const float4v*)(b + t * 4);
    ushort4v o;
    #pragma unroll
    for (int j = 0; j < 4; ++j) o[j] = f2bf((v[j] - mu) * rstd * gv[j] + bv[j]);
    *(ushort4v*)(z + (size_t)row * CDIM + t * 4) = o;
  } else {
    const int idx = (bid - MROWS) * 256 + t;
    const int e = idx * 4;
    if (e < W1ELEMS) {
      const int row = e >> 10;
      const int srow = row < 1024 ? row : row + 1024;
      const float4v v = *(const float4v*)(w_in + (size_t)srow * 1024 + (e & 1023));
      ushort4v o;
      #pragma unroll
      for (int j = 0; j < 4; ++j) o[j] = f2bf(v[j]);
      *(ushort4v*)(wqv + e) = o;
    } else if (e < W1ELEMS + W2ELEMS) {
      const int e2 = e - W1ELEMS;
      const float4v v = *(const float4v*)(w_out + e2);
      ushort4v o;
      #pragma unroll
      for (int j = 0; j < 4; ++j) o[j] = f2bf(v[j]);
      *(ushort4v*)(wo + e2) = o;
    } else {
      const int pidx = idx - (W1ELEMS + W2ELEMS) / 4;   // 0..262143
      const int ic = pidx >> 3, part = pidx & 7;
      *(uint4v*)(vt + (size_t)ic * SPAD + 576 + part * 8) = (uint4v)0u;
    }
  }
}

// ---------------- qv GEMM (R11-proven): 256x256, 16 waves 64x64, BK=64 dbuf ----------------
__global__ __launch_bounds__(1024, 4) void gemm_qv(const unsigned short* __restrict__ A,
                                                   const unsigned short* __restrict__ B,
                                                   const float* __restrict__ bias,
                                                   unsigned short* __restrict__ qout,
                                                   unsigned short* __restrict__ vtout) {
  __shared__ char smem[131072];  // buf b at b*65536: A [256][64] @0 (32KB), B @32768
  const int t = threadIdx.x;
  const int w = t >> 6, l = t & 63;
  const int L = (blockIdx.x & 7) * 73 + (blockIdx.x >> 3);   // bijective: 584=8*73
  const int p = L >> 3, c = L & 7;
  const int m0 = p * 256, n0 = c * 256;
  const int wm = w >> 2, wn = w & 3;
  const int g4 = (l >> 4) * 4;
  const int fr = l & 15;
  const int fb = (l >> 4) * 16;
  const int sw = (l & 7) << 4;

  f32x4 acc[4][4];
  #pragma unroll
  for (int i = 0; i < 4; ++i)
    #pragma unroll
    for (int j = 0; j < 4; ++j) acc[i][j] = (f32x4)0.0f;

  const int srow = l >> 3;
  const int scol = ((((l & 7) * 16) ^ ((srow & 7) << 4)) >> 1);
  int ra0 = m0 + w * 16 + srow;     if (ra0 > MROWS - 1) ra0 = MROWS - 1;
  int ra1 = m0 + w * 16 + 8 + srow; if (ra1 > MROWS - 1) ra1 = MROWS - 1;
  const unsigned short* pA0 = A + (size_t)ra0 * 1024 + scol;
  const unsigned short* pA1 = A + (size_t)ra1 * 1024 + scol;
  const unsigned short* pB0 = B + (size_t)(n0 + w * 16 + srow) * 1024 + scol;
  const unsigned short* pB1 = pB0 + (size_t)8 * 1024;

  #define STG(kt, buf)                                                     \
    {                                                                      \
      char* const dA_ = smem + (buf) * 65536 + w * 2048;                   \
      char* const dB_ = dA_ + 32768;                                       \
      const int k0_ = (kt) * 64;                                           \
      load_lds16(pA0 + k0_, dA_);                                          \
      load_lds16(pA1 + k0_, dA_ + 1024);                                   \
      load_lds16(pB0 + k0_, dB_);                                          \
      load_lds16(pB1 + k0_, dB_ + 1024);                                   \
    }

  STG(0, 0)
  __syncthreads();

  for (int kb = 0; kb < 16; ++kb) {
    const int b = kb & 1;
    if (kb < 15) STG(kb + 1, b ^ 1)
    const char* Ab = smem + b * 65536;
    const char* Bb = Ab + 32768;
    #pragma unroll
    for (int kk = 0; kk < 2; ++kk) {
      bf16x8 af[4], bfr[4];
      #pragma unroll
      for (int i = 0; i < 4; ++i)
        af[i] = *(const bf16x8*)(Ab + (wm * 64 + i * 16 + fr) * 128 + ((kk * 64 + fb) ^ sw));
      #pragma unroll
      for (int j = 0; j < 4; ++j)
        bfr[j] = *(const bf16x8*)(Bb + (wn * 64 + j * 16 + fr) * 128 + ((kk * 64 + fb) ^ sw));
      #pragma unroll
      for (int i = 0; i < 4; ++i)
        #pragma unroll
        for (int j = 0; j < 4; ++j)
          acc[i][j] = __builtin_amdgcn_mfma_f32_16x16x32_bf16(af[i], bfr[j], acc[i][j], 0, 0, 0);
    }
    __syncthreads();
  }
  #undef STG

  unsigned short* sm = (unsigned short*)smem;   // [64][264] b16 per pass
  const bool isq = (n0 < 1024);
  const float* bb = isq ? (bias + n0) : (bias + 1024 + n0);
  const float scl = isq ? SQC : 1.0f;
  float bcol[4];
  #pragma unroll
  for (int j = 0; j < 4; ++j) bcol[j] = bb[wn * 64 + j * 16 + fr];
  for (int pass = 0; pass < 4; ++pass) {
    if (wm == pass) {
      #pragma unroll
      for (int i = 0; i < 4; ++i)
        #pragma unroll
        for (int j = 0; j < 4; ++j)
          #pragma unroll
          for (int r = 0; r < 4; ++r)
            sm[(i * 16 + g4 + r) * 264 + wn * 64 + j * 16 + fr] =
                f2bf((acc[i][j][r] + bcol[j]) * scl);
    }
    __syncthreads();
    if (isq) {
      #pragma unroll
      for (int it = 0; it < 2; ++it) {
        const int cid = it * 1024 + t;
        const int row = cid >> 5, ch = cid & 31;
        const int grow = m0 + pass * 64 + row;
        if (grow < MROWS)
          *(uint4v*)(qout + (size_t)grow * 1024 + n0 + ch * 8) =
              *(const uint4v*)(sm + row * 264 + ch * 8);
      }
    } else {
      const int tokloc = t & 63, chgrp = t >> 6;   // 16 groups of 16 channels
      const int token = m0 + pass * 64 + tokloc;
      if (token < MROWS) {
        const unsigned int nimg = (unsigned int)token / 577u;
        const int s = token - (int)(nimg * 577u);
        unsigned short* op =
            vtout + ((size_t)nimg * 1024 + (n0 - 1024) + chgrp * 16) * SPAD + s;
        const unsigned short* sp = sm + tokloc * 264 + chgrp * 16;
        #pragma unroll 8
        for (int it = 0; it < 16; ++it)
          op[(size_t)it * SPAD] = sp[it];
      }
    }
    __syncthreads();
  }
}

// ---------------- proj GEMM (R15-proven): 256x128 tile, 16 waves 64x32, BK=64 dbuf ----------------
__global__ __launch_bounds__(1024, 4) void gemm_proj(const unsigned short* __restrict__ A,
                                                     const unsigned short* __restrict__ B,
                                                     const float* __restrict__ bias,
                                                     float* __restrict__ outp) {
  __shared__ char smem[98304];  // buf b at b*49152: A [256][64] @0 (32KB), B [128][64] @32768
  const int t = threadIdx.x;
  const int w = t >> 6, l = t & 63;
  const int L = (blockIdx.x & 7) * 73 + (blockIdx.x >> 3);   // bijective: 584=8*73
  const int p = L >> 3, c = L & 7;
  const int m0 = p * 256, n0 = c * 128;
  const int wm = w >> 2, wn = w & 3;
  const int g4 = (l >> 4) * 4;
  const int fr = l & 15;
  const int fb = (l >> 4) * 16;
  const int sw = (l & 7) << 4;

  f32x4 acc[4][2];
  #pragma unroll
  for (int i = 0; i < 4; ++i)
    #pragma unroll
    for (int j = 0; j < 2; ++j) acc[i][j] = (f32x4)0.0f;

  const int srow = l >> 3;
  const int scol = ((((l & 7) * 16) ^ ((srow & 7) << 4)) >> 1);
  int ra0 = m0 + w * 16 + srow;     if (ra0 > MROWS - 1) ra0 = MROWS - 1;
  int ra1 = m0 + w * 16 + 8 + srow; if (ra1 > MROWS - 1) ra1 = MROWS - 1;
  const unsigned short* pA0 = A + (size_t)ra0 * 1024 + scol;
  const unsigned short* pA1 = A + (size_t)ra1 * 1024 + scol;
  const unsigned short* pB0 = B + (size_t)(n0 + w * 8 + srow) * 1024 + scol;  // 16 waves x 8 rows

  #define STG(kt, buf)                                                     \
    {                                                                      \
      char* const dA_ = smem + (buf) * 49152 + w * 2048;                   \
      const int k0_ = (kt) * 64;                                           \
      load_lds16(pA0 + k0_, dA_);                                          \
      load_lds16(pA1 + k0_, dA_ + 1024);                                   \
      load_lds16(pB0 + k0_, smem + (buf) * 49152 + 32768 + w * 1024);      \
    }

  STG(0, 0)
  __syncthreads();

  for (int kb = 0; kb < 16; ++kb) {
    const int b = kb & 1;
    if (kb < 15) STG(kb + 1, b ^ 1)
    const char* Ab = smem + b * 49152;
    const char* Bb = Ab + 32768;
    #pragma unroll
    for (int kk = 0; kk < 2; ++kk) {
      bf16x8 af[4], bfr[2];
      #pragma unroll
      for (int i = 0; i < 4; ++i)
        af[i] = *(const bf16x8*)(Ab + (wm * 64 + i * 16 + fr) * 128 + ((kk * 64 + fb) ^ sw));
      #pragma unroll
      for (int j = 0; j < 2; ++j)
        bfr[j] = *(const bf16x8*)(Bb + (wn * 32 + j * 16 + fr) * 128 + ((kk * 64 + fb) ^ sw));
      #pragma unroll
      for (int i = 0; i < 4; ++i)
        #pragma unroll
        for (int j = 0; j < 2; ++j)
          acc[i][j] = __builtin_amdgcn_mfma_f32_16x16x32_bf16(af[i], bfr[j], acc[i][j], 0, 0, 0);
    }
    __syncthreads();
  }
  #undef STG

  // fp32 epilogue: eight 32-row passes, [32][132] f32 = 16.9KB
  float* smf = (float*)smem;
  float bcol[2];
  #pragma unroll
  for (int j = 0; j < 2; ++j) bcol[j] = bias[n0 + wn * 32 + j * 16 + fr];
  for (int q8 = 0; q8 < 8; ++q8) {
    if (wm == (q8 >> 1)) {
      const int i0 = (q8 & 1) * 2;
      #pragma unroll
      for (int i2 = 0; i2 < 2; ++i2)
        #pragma unroll
        for (int j = 0; j < 2; ++j)
          #pragma unroll
          for (int r = 0; r < 4; ++r)
            smf[(i2 * 16 + g4 + r) * 132 + wn * 32 + j * 16 + fr] =
                acc[i0 + i2][j][r] + bcol[j];
    }
    __syncthreads();
    {
      const int row = t >> 5, ch = t & 31;        // 32 rows x 128 cols, 1 float4/thread
      const int grow = m0 + q8 * 32 + row;
      if (grow < MROWS)
        *(float4v*)(outp + (size_t)grow * 1024 + n0 + ch * 4) =
            *(const float4v*)(smf + row * 132 + ch * 4);
    }
    __syncthreads();
  }
}

// ---------------- flash attention (R15-proven 4-wave, no setprio) ----------------
__global__ __launch_bounds__(256) void attn_kernel(const unsigned short* __restrict__ qbuf,
                                                   const unsigned short* __restrict__ vt,
                                                   unsigned short* __restrict__ out) {
  __shared__ char smem[32768];  // buf b at b*16384: K 8KB, V^T 8KB
  const int t = threadIdx.x, w = t >> 6, l = t & 63;
  const int g = l >> 4, fr = l & 15;
  const int bid = blockIdx.x;
  const int xcd = bid & 7, idx = bid >> 3;
  const int nhl = idx / 5;
  const int qb = idx - nhl * 5;
  const int nh = xcd * 64 + nhl;
  const int n = nh >> 4, h = nh & 15;
  const size_t rowbase = (size_t)n * SEQ;
  const int sw = (l & 7) << 4;

  bf16x8 bq[2][2];
  #pragma unroll
  for (int half = 0; half < 2; ++half) {
    const unsigned short* qp =
        qbuf + (rowbase + qb * 128 + half * 64 + w * 16 + fr) * 1024 + h * 64 + g * 8;
    bq[half][0] = *(const bf16x8*)qp;
    bq[half][1] = *(const bf16x8*)(qp + 32);
  }

  const int srow = l >> 3;
  const int scolE = ((((l & 7) * 16) ^ ((srow & 7) << 4)) >> 1);
  const unsigned short* ksrc = qbuf + (rowbase + w * 16 + srow) * 1024 + h * 64 + scolE;
  const unsigned short* vsrc = vt + ((size_t)nh * 64 + w * 16 + srow) * SPAD + scolE;

  f32x4 acc[2][4];
  #pragma unroll
  for (int half = 0; half < 2; ++half)
    #pragma unroll
    for (int cf = 0; cf < 4; ++cf) acc[half][cf] = (f32x4)0.0f;
  float l_run[2] = {0.0f, 0.0f};

  {
    char* kdst = smem + (w * 16) * 128;
    char* vdst = smem + 8192 + (w * 16) * 128;
    load_lds16(ksrc, kdst);
    load_lds16(ksrc + (size_t)8 * 1024, kdst + 1024);
    load_lds16(vsrc, vdst);
    load_lds16(vsrc + 8 * SPAD, vdst + 1024);
  }
  __syncthreads();

  for (int kb = 0; kb < 10; ++kb) {
    const int b = kb & 1;
    const char* kbuf = smem + b * 16384;
    const char* vbuf = kbuf + 8192;

    if (kb < 9) {
      char* kdst = smem + (b ^ 1) * 16384 + (w * 16) * 128;
      char* vdst = kdst + 8192;
      load_lds16(ksrc + (size_t)((kb + 1) * 64) * 1024, kdst);
      load_lds16(ksrc + (size_t)((kb + 1) * 64 + 8) * 1024, kdst + 1024);
      load_lds16(vsrc + (kb + 1) * 64, vdst);
      load_lds16(vsrc + 8 * SPAD + (kb + 1) * 64, vdst + 1024);
    }

    f32x4 s4[2][4];
    #pragma unroll
    for (int half = 0; half < 2; ++half)
      #pragma unroll
      for (int cf = 0; cf < 4; ++cf) s4[half][cf] = (f32x4)0.0f;
    #pragma unroll
    for (int kk = 0; kk < 2; ++kk)
      #pragma unroll
      for (int cf = 0; cf < 4; ++cf) {
        const bf16x8 af = *(const bf16x8*)(kbuf + (cf * 16 + fr) * 128 + ((kk * 64 + g * 16) ^ sw));
        s4[0][cf] = __builtin_amdgcn_mfma_f32_16x16x32_bf16(af, bq[0][kk], s4[0][cf], 0, 0, 0);
        s4[1][cf] = __builtin_amdgcn_mfma_f32_16x16x32_bf16(af, bq[1][kk], s4[1][cf], 0, 0, 0);
      }

    if (kb == 9) {
      #pragma unroll
      for (int half = 0; half < 2; ++half) {
        #pragma unroll
        for (int cf = 0; cf < 4; ++cf)
          #pragma unroll
          for (int r = 0; r < 4; ++r)
            if (cf != 0 || r != 0) s4[half][cf][r] = -__builtin_inff();
        s4[half][0][0] = (g == 0) ? s4[half][0][0] : -__builtin_inff();
      }
    }

    bf16x8 ap[2][2];
    #pragma unroll
    for (int half = 0; half < 2; ++half) {
      float sum = 0.0f;
      #pragma unroll
      for (int cf = 0; cf < 4; ++cf)
        #pragma unroll
        for (int r = 0; r < 4; ++r) {
          const float p2 = __builtin_amdgcn_exp2f(s4[half][cf][r]);
          s4[half][cf][r] = p2;
          sum += p2;
        }
      sum += __shfl_xor(sum, 16);
      sum += __shfl_xor(sum, 32);
      l_run[half] += sum;

      unsigned int pka[4], pkb[4];
      #pragma unroll
      for (int cf = 0; cf < 4; ++cf) {
        asm("v_cvt_pk_bf16_f32 %0, %1, %2" : "=v"(pka[cf]) : "v"(s4[half][cf][0]), "v"(s4[half][cf][1]));
        asm("v_cvt_pk_bf16_f32 %0, %1, %2" : "=v"(pkb[cf]) : "v"(s4[half][cf][2]), "v"(s4[half][cf][3]));
      }
      #pragma unroll
      for (int kk = 0; kk < 2; ++kk) {
        unsigned int a0 = pka[2 * kk], b0 = pka[2 * kk + 1];
        unsigned int a1 = pkb[2 * kk], b1 = pkb[2 * kk + 1];
        asm("v_permlane32_swap_b32 %0, %1" : "+v"(a0), "+v"(b0));
        asm("v_permlane16_swap_b32 %0, %1" : "+v"(a0), "+v"(b0));
        asm("v_permlane32_swap_b32 %0, %1" : "+v"(a1), "+v"(b1));
        asm("v_permlane16_swap_b32 %0, %1" : "+v"(a1), "+v"(b1));
        union { unsigned int i[4]; bf16x8 v; } u;
        u.i[0] = a0; u.i[1] = a1; u.i[2] = b0; u.i[3] = b1;
        ap[half][kk] = u.v;
      }
    }

    #pragma unroll
    for (int kk = 0; kk < 2; ++kk)
      #pragma unroll
      for (int cf = 0; cf < 4; ++cf) {
        const bf16x8 bv = *(const bf16x8*)(vbuf + (cf * 16 + fr) * 128 + ((kk * 64 + g * 16) ^ sw));
        acc[0][cf] = __builtin_amdgcn_mfma_f32_16x16x32_bf16(ap[0][kk], bv, acc[0][cf], 0, 0, 0);
        acc[1][cf] = __builtin_amdgcn_mfma_f32_16x16x32_bf16(ap[1][kk], bv, acc[1][cf], 0, 0, 0);
      }

    __syncthreads();
  }

  #pragma unroll
  for (int half = 0; half < 2; ++half) {
    const float rcp = 1.0f / l_run[half];
    #pragma unroll
    for (int r = 0; r < 4; ++r) {
      const float rr = __shfl(rcp, g * 4 + r);
      const int qg = qb * 128 + half * 64 + w * 16 + g * 4 + r;
      if (qg < SEQ) {
        #pragma unroll
        for (int cf = 0; cf < 4; ++cf)
          out[(rowbase + qg) * 1024 + h * 64 + cf * 16 + fr] = f2bf(acc[half][cf][r] * rr);
      }
    }
  }
}

extern "C" void kernel_launch(void* const* d_in, const int* in_sizes, int n_in,
                              void* d_out, int out_size, void* d_ws, size_t ws_size,
                              hipStream_t stream) {
  const float* x     = (const float*)d_in[0];
  const float* ln_g  = (const float*)d_in[1];
  const float* ln_b  = (const float*)d_in[2];
  const float* w_in  = (const float*)d_in[3];
  const float* b_in  = (const float*)d_in[4];
  const float* w_out = (const float*)d_in[5];
  const float* b_out = (const float*)d_in[6];

  unsigned short* z    = (unsigned short*)d_ws;            // [MROWS][1024] bf16; reused as attn_out
  unsigned short* qbuf = z + (size_t)MROWS * 1024;         // [MROWS][1024] bf16 (q = k, pre-scaled)
  unsigned short* vt   = qbuf + (size_t)MROWS * 1024;      // [32*1024][640] bf16 (V^T)
  unsigned short* wqv  = vt + (size_t)512 * 64 * SPAD;     // [2048][1024] bf16
  unsigned short* wo   = wqv + (size_t)2048 * 1024;        // [1024][1024] bf16

  prep_kernel<<<MROWS + 4096, 256, 0, stream>>>(x, ln_g, ln_b, w_in, w_out, z, wqv, wo, vt);
  gemm_qv<<<584, 1024, 0, stream>>>(z, wqv, b_in, qbuf, vt);
  attn_kernel<<<2560, 256, 0, stream>>>(qbuf, vt, z);
  gemm_proj<<<584, 1024, 0, stream>>>(z, wo, b_out, (float*)d_out);
}